// Round 3
// baseline (46900.739 us; speedup 1.0000x reference)
//
#include <hip/hip_runtime.h>
#include <hip/hip_bf16.h>

// GRU backbone: B=64 S=2048 D=256 V=256 L=4
// R3: lean flipped-operand scan. Wh = MFMA A operand (register frags), h = B operand.
//   - gi stored transposed giT[s][gc][b]: gate inputs read as direct coalesced global
//     ushort loads (no LDS staging, no DMA, no per-step vmcnt prefetch drain).
//   - h update: lane owns 4 consecutive d -> 2x ds_write_b64 (conflict-benign).
//   - output via small padded LDS transpose buf, 1 coalesced b128 store/thread/step
//     into seqT[s][b][d]; all inter-layer activations live transposed.

#define B_ 64
#define S_ 2048
#define D_ 256
#define V_ 256
#define L_ 4

typedef short  s16x8 __attribute__((ext_vector_type(8)));
typedef short  s16x4 __attribute__((ext_vector_type(4)));
typedef float  f32x4 __attribute__((ext_vector_type(4)));

static __device__ __forceinline__ unsigned short f2b(float f){
  union { float f; unsigned int u; } v; v.f = f;
  unsigned int u = v.u;
  return (unsigned short)((u + 0x7FFFu + ((u >> 16) & 1u)) >> 16);  // RNE
}
static __device__ __forceinline__ float b2f(unsigned short s){
  union { unsigned int u; float f; } v; v.u = ((unsigned int)s) << 16; return v.f;
}

static __device__ __forceinline__ void lds_load16(void* lds, const void* g){
  __builtin_amdgcn_global_load_lds(
      (const __attribute__((address_space(1))) unsigned int*)g,
      (__attribute__((address_space(3))) unsigned int*)lds, 16, 0, 0);
}

__global__ void cast_bf16_kernel(const float* __restrict__ src,
                                 unsigned short* __restrict__ dst, int n){
  int i = blockIdx.x * 256 + threadIdx.x;
  if (i < n) dst[i] = f2b(src[i]);
}

// seqT[s][b][d]
__global__ void embed_kernel(const int* __restrict__ x, const float* __restrict__ emb,
                             unsigned short* __restrict__ seqT){
  int bid = blockIdx.x;
  int b = bid >> 11, s = bid & 2047;
  int d = threadIdx.x;
  int tok = x[b * S_ + s];
  seqT[((size_t)s * B_ + b) * D_ + d] = f2b(emb[tok * D_ + d]);
}

// MODE 0: A=Wih[768xK] B=seqT[131072xK] row-bias -> giT[s][gc][b] bf16
// MODE 1: A=seqT[131072xK] B=Wout[256xK] col-bias -> out[b][s][v] f32
template<int MODE>
__global__ __launch_bounds__(256) void gemm2(const unsigned short* __restrict__ A,
                                             const unsigned short* __restrict__ Bw,
                                             const float* __restrict__ bias,
                                             void* __restrict__ Cp, int K){
  __shared__ __align__(16) unsigned short As[128 * 32];
  __shared__ __align__(16) unsigned short Bs[128 * 32];
  const int tid = threadIdx.x, lane = tid & 63, w = tid >> 6;
  const int col = lane & 15, q = lane >> 4;
  const int m0 = blockIdx.x * 128, n0 = blockIdx.y * 128;
  const int mW = (w & 1) * 64, nW = (w >> 1) * 64;
  const size_t rowb = (size_t)K * 2;

  f32x4 acc[4][4] = {};

  for (int k0 = 0; k0 < K; k0 += 32){
    __syncthreads();
    #pragma unroll
    for (int inst = 0; inst < 2; ++inst){
      int c = inst * 256 + w * 64 + lane;
      int row = c >> 2, c16 = c & 3;
      lds_load16((char*)As + (inst * 4096 + w * 1024),
                 (const char*)A  + (size_t)(m0 + row) * rowb + (size_t)k0 * 2 + c16 * 16);
      lds_load16((char*)Bs + (inst * 4096 + w * 1024),
                 (const char*)Bw + (size_t)(n0 + row) * rowb + (size_t)k0 * 2 + c16 * 16);
    }
    __syncthreads();
    s16x8 aF[4], bF[4];
    #pragma unroll
    for (int t = 0; t < 4; ++t){
      aF[t] = *(const s16x8*)&As[(mW + t * 16 + col) * 32 + q * 8];
      bF[t] = *(const s16x8*)&Bs[(nW + t * 16 + col) * 32 + q * 8];
    }
    #pragma unroll
    for (int mi = 0; mi < 4; ++mi)
      #pragma unroll
      for (int ni = 0; ni < 4; ++ni)
        acc[mi][ni] = __builtin_amdgcn_mfma_f32_16x16x32_bf16(aF[mi], bF[ni], acc[mi][ni], 0, 0, 0);
  }

  if (MODE == 0){
    f32x4 brv[4];
    #pragma unroll
    for (int mi = 0; mi < 4; ++mi) brv[mi] = *(const f32x4*)(bias + m0 + mW + mi * 16 + 4 * q);
    #pragma unroll
    for (int mi = 0; mi < 4; ++mi)
      #pragma unroll
      for (int ni = 0; ni < 4; ++ni)
        #pragma unroll
        for (int i = 0; i < 4; ++i){
          int r = m0 + mW + mi * 16 + 4 * q + i;       // gc row
          int n = n0 + nW + ni * 16 + col;             // (s,b) col
          float v = acc[mi][ni][i] + brv[mi][i];
          ((unsigned short*)Cp)[(size_t)(n >> 6) * (768 * 64) + (size_t)r * 64 + (n & 63)] = f2b(v);
        }
  } else {
    float bn[4];
    #pragma unroll
    for (int ni = 0; ni < 4; ++ni) bn[ni] = bias[n0 + nW + ni * 16 + col];
    #pragma unroll
    for (int mi = 0; mi < 4; ++mi)
      #pragma unroll
      for (int ni = 0; ni < 4; ++ni)
        #pragma unroll
        for (int i = 0; i < 4; ++i){
          int m = m0 + mW + mi * 16 + 4 * q + i;       // (s,b) row
          int n = n0 + nW + ni * 16 + col;             // v col
          ((float*)Cp)[((size_t)(m & 63) * S_ + (m >> 6)) * V_ + n] = acc[mi][ni][i] + bn[ni];
        }
  }
}

// Recurrent scan, one layer. giT: [S][768][64] bf16 ; Wh: [768][256] bf16 ; bh: [768] f32
// outT: [S][64][256] bf16. Grid = 4 (batch tiles of 16), block = 512 (8 waves).
#define L2E 1.44269504f
#define OBS 264   // obuf row stride (shorts): 256+8 pad -> 528 B (16B-multiple, banks spread)
__global__ __launch_bounds__(512, 2) void gru_scan(const unsigned short* __restrict__ giT,
                                                   const unsigned short* __restrict__ Wh,
                                                   const float* __restrict__ bh,
                                                   unsigned short* __restrict__ outT){
  __shared__ __align__(16) unsigned short hb[2][4096];      // h dbuf, B-frag order
  __shared__ __align__(16) unsigned short ob[2][16 * OBS];  // out transpose dbuf
  const int tid = threadIdx.x, lane = tid & 63, w = tid >> 6;
  const int col = lane & 15, q = lane >> 4;
  const int b0 = blockIdx.x * 16;
  const int dbase = w * 32;   // wave owns d in [dbase, dbase+32)

  // Wh as MFMA-A fragments: A[m=lane&15][k=8q+j]; tile rows = gate cols
  s16x8 bw[3][2][8];
  f32x4 bhv[3][2];
  #pragma unroll
  for (int g = 0; g < 3; ++g)
    #pragma unroll
    for (int t2 = 0; t2 < 2; ++t2){
      const int tb = g * 256 + dbase + t2 * 16;
      #pragma unroll
      for (int kk = 0; kk < 8; ++kk)
        bw[g][t2][kk] = *(const s16x8*)(Wh + (size_t)(tb + col) * 256 + kk * 32 + q * 8);
      bhv[g][t2] = *(const f32x4*)(bh + tb + 4 * q);   // regs i -> rows 4q+i
    }

  // per-(g,t2) gi pointers: giT[s][gc=tb+4q+i][b0+col], i folds into imm offset
  const unsigned short* gp[3][2];
  #pragma unroll
  for (int g = 0; g < 3; ++g)
    #pragma unroll
    for (int t2 = 0; t2 < 2; ++t2)
      gp[g][t2] = giT + (size_t)(g * 256 + dbase + t2 * 16 + 4 * q) * 64 + b0 + col;

  for (int i = tid; i < 4096; i += 512) hb[0][i] = 0;   // h0 = 0
  float hprev[2][4] = {};

  // flush indexing: thread -> (m, 16B chunk)
  const int fm = tid >> 5, fc = tid & 31;

  __syncthreads();

  for (int s = 0; s < S_; ++s){
    const int cur = s & 1, nxt = cur ^ 1;

    // issue gi loads for this step (coalesced 4-seg ushort loads, latency hidden by MFMA)
    unsigned short gv[3][2][4];
    #pragma unroll
    for (int g = 0; g < 3; ++g)
      #pragma unroll
      for (int t2 = 0; t2 < 2; ++t2)
        #pragma unroll
        for (int i = 0; i < 4; ++i)
          gv[g][t2][i] = gp[g][t2][i * 64];

    // flush previous step's out chunk (LDS->global, coalesced)
    if (s > 0){
      s16x8 v = *(const s16x8*)&ob[nxt][fm * OBS + fc * 8];
      *(s16x8*)(outT + ((size_t)(s - 1) * B_ + b0 + fm) * D_ + fc * 8) = v;
    }

    // gh = Wh(A) x h(B) + bh
    f32x4 acc[3][2];
    #pragma unroll
    for (int g = 0; g < 3; ++g)
      #pragma unroll
      for (int t2 = 0; t2 < 2; ++t2) acc[g][t2] = bhv[g][t2];

    const unsigned short* hc = hb[cur];
    #pragma unroll
    for (int kk = 0; kk < 8; ++kk){
      s16x8 hf = *(const s16x8*)&hc[kk * 512 + lane * 8];
      #pragma unroll
      for (int g = 0; g < 3; ++g)
        #pragma unroll
        for (int t2 = 0; t2 < 2; ++t2)
          acc[g][t2] = __builtin_amdgcn_mfma_f32_16x16x32_bf16(bw[g][t2][kk], hf, acc[g][t2], 0, 0, 0);
    }

    // gates: lane holds (gc = tb+4q+i, m = col) -> h_new for (m=col, d=dbase+16t2+4q+i)
    #pragma unroll
    for (int t2 = 0; t2 < 2; ++t2){
      const int d0 = dbase + t2 * 16 + 4 * q;
      s16x4 hw;
      #pragma unroll
      for (int i = 0; i < 4; ++i){
        float pr = acc[0][t2][i] + b2f(gv[0][t2][i]);
        float pz = acc[1][t2][i] + b2f(gv[1][t2][i]);
        float giN = b2f(gv[2][t2][i]);
        float ea = __builtin_amdgcn_exp2f(-pr * L2E);
        float eb = __builtin_amdgcn_exp2f(-pz * L2E);
        float wa = 1.f + ea, wb = 1.f + eb;
        float wr = __builtin_amdgcn_rcpf(wa * wb);
        float rg = wr * wb;
        float zg = wr * wa;
        float na = giN + rg * acc[2][t2][i];
        float u  = __builtin_amdgcn_exp2f(na * (2.f * L2E));
        float ng = 1.f - 2.f * __builtin_amdgcn_rcpf(u + 1.f);   // tanh
        float hn = ng + zg * (hprev[t2][i] - ng);
        hprev[t2][i] = hn;
        hw[i] = (short)f2b(hn);
      }
      // h exchange: 4 consecutive d per lane -> one b64, B-frag order
      const int ha = w * 512 + (col + 16 * ((2 * t2 + (q >> 1)) & 3)) * 8 + 4 * (q & 1);
      *(s16x4*)&hb[nxt][ha] = hw;
      // out transpose buffer
      *(s16x4*)&ob[cur][col * OBS + d0] = hw;
    }
    __syncthreads();

    // advance gi pointers
    #pragma unroll
    for (int g = 0; g < 3; ++g)
      #pragma unroll
      for (int t2 = 0; t2 < 2; ++t2) gp[g][t2] += 768 * 64;
  }

  // epilogue: flush last step
  {
    s16x8 v = *(const s16x8*)&ob[(S_ - 1) & 1][fm * OBS + fc * 8];
    *(s16x8*)(outT + ((size_t)(S_ - 1) * B_ + b0 + fm) * D_ + fc * 8) = v;
  }
}

extern "C" void kernel_launch(void* const* d_in, const int* in_sizes, int n_in,
                              void* d_out, int out_size, void* d_ws, size_t ws_size,
                              hipStream_t stream){
  const int*   x    = (const int*)  d_in[0];
  const float* emb  = (const float*)d_in[1];
  const float* Wih  = (const float*)d_in[2];
  const float* Whh  = (const float*)d_in[3];
  const float* bih  = (const float*)d_in[4];
  const float* bhh  = (const float*)d_in[5];
  const float* Wout = (const float*)d_in[6];
  const float* bout = (const float*)d_in[7];
  float* out = (float*)d_out;

  char* ws = (char*)d_ws;
  unsigned short* seqA  = (unsigned short*)(ws);                 //  67,108,864 B [S][B][D]
  unsigned short* seqB  = (unsigned short*)(ws +  67108864);     //  67,108,864 B
  unsigned short* giT   = (unsigned short*)(ws + 134217728);     // 201,326,592 B [S][768][64]
  unsigned short* wihB  = (unsigned short*)(ws + 335544320);     //   1,572,864 B
  unsigned short* whhB  = (unsigned short*)(ws + 337117184);     //   1,572,864 B
  unsigned short* woutB = (unsigned short*)(ws + 338690048);     //     131,072 B

  cast_bf16_kernel<<<3072, 256, 0, stream>>>(Wih,  wihB,  L_ * 768 * 256);
  cast_bf16_kernel<<<3072, 256, 0, stream>>>(Whh,  whhB,  L_ * 768 * 256);
  cast_bf16_kernel<<< 256, 256, 0, stream>>>(Wout, woutB, V_ * D_);
  embed_kernel<<<B_ * S_, 256, 0, stream>>>(x, emb, seqA);

  unsigned short* sIn = seqA;
  unsigned short* sOut = seqB;
  for (int l = 0; l < L_; ++l){
    gemm2<0><<<dim3(6, 1024), 256, 0, stream>>>(wihB + (size_t)l * 768 * 256, sIn,
                                                bih + l * 768, giT, 256);
    gru_scan<<<4, 512, 0, stream>>>(giT, whhB + (size_t)l * 768 * 256, bhh + l * 768, sOut);
    unsigned short* t = sIn; sIn = sOut; sOut = t;
  }
  gemm2<1><<<dim3(1024, 2), 256, 0, stream>>>(sIn, woutB, bout, out, 256);
}